// Round 3
// baseline (116.145 us; speedup 1.0000x reference)
//
#include <hip/hip_runtime.h>
#include <math.h>

#define NB 4096
#define ND 128

#define SCALE_POS 2.0f
#define SCALE_NEG 50.0f
#define THRESH    0.7f
#define MARGIN    0.1f
#define GAMMA     0.3f
#define EPS_SELF  1e-5f

typedef __attribute__((ext_vector_type(8))) short s16x8;
typedef __attribute__((ext_vector_type(4))) float f32x4;

// Monotone float<->uint key (order-preserving incl +-inf)
__device__ __forceinline__ unsigned int fkey(float f) {
  unsigned int u = __float_as_uint(f);
  return (u & 0x80000000u) ? ~u : (u | 0x80000000u);
}
__device__ __forceinline__ float keyf(unsigned int k) {
  unsigned int u = (k & 0x80000000u) ? (k & 0x7FFFFFFFu) : ~k;
  return __uint_as_float(u);
}
__device__ __forceinline__ short f2bf(float x) {  // RNE to bf16
  unsigned u = __float_as_uint(x);
  unsigned r = (u + 0x7FFFu + ((u >> 16) & 1u)) >> 16;
  return (short)r;
}
__device__ __forceinline__ float bf2f(short h) {
  return __uint_as_float(((unsigned)(unsigned short)h) << 16);
}

// ---------------------------------------------------------------------------
// K1: fp32 -> split-bf16 directly into fragment-major F layout.
// F chunk index t = tile*256 + s*64 + lg*16 + lm16 holds row (tile*16+lm16),
// k = (s*4+lg)*8 .. +8. A wave's fragment load at (tile,s) is then F[base + l]
// -> fully coalesced 1KB. Coalesced WRITES here (scattered reads from L2).
__global__ __launch_bounds__(256) void k1_convert(
    const float* __restrict__ emb, short* __restrict__ Fhi, short* __restrict__ Flo,
    unsigned long long* __restrict__ minkey, unsigned int* __restrict__ maxkey,
    float* __restrict__ possum, float* __restrict__ negsum) {
  int t = blockIdx.x * 256 + threadIdx.x;  // 65536 chunks of 8 floats
  int lm16 = t & 15, lg = (t >> 4) & 3, s = (t >> 6) & 3, tile = t >> 8;
  int r = tile * 16 + lm16;
  int c = s * 4 + lg;
  const float4* e4 = (const float4*)emb;
  float4 v0 = e4[r * 32 + c * 2];
  float4 v1 = e4[r * 32 + c * 2 + 1];
  float xs[8] = {v0.x, v0.y, v0.z, v0.w, v1.x, v1.y, v1.z, v1.w};
  s16x8 h, l;
#pragma unroll
  for (int e = 0; e < 8; ++e) {
    short hh = f2bf(xs[e]);
    h[e] = hh;
    l[e] = f2bf(xs[e] - bf2f(hh));
  }
  ((s16x8*)Fhi)[t] = h;
  ((s16x8*)Flo)[t] = l;
  if (t < NB) {
    minkey[t] = 0xFF800000FFFFFFFFULL;  // (+inf key, idx ~0)
    maxkey[t] = 0x007FFFFFu;            // -inf key
    possum[t] = 0.0f;
    negsum[t] = 0.0f;
  }
}

// ---------------------------------------------------------------------------
// K2a (pass 1): Gram min/max reduction only — NO sim stores.
// Block 128x128 (4 waves, 64x64 each), fragments straight from F (coalesced).
__global__ __launch_bounds__(256) void k2a_pass1(
    const short* __restrict__ Fhi, const short* __restrict__ Flo,
    const int* __restrict__ labels,
    unsigned long long* __restrict__ minkey, unsigned int* __restrict__ maxkey) {
  int tid = threadIdx.x;
  int w = tid >> 6, l = tid & 63;
  int lm16 = l & 15, lg = l >> 4;
  int mt0 = blockIdx.y * 8 + (w >> 1) * 4;  // 16-row tile indices
  int nt0 = blockIdx.x * 8 + (w & 1) * 4;
  const s16x8* FH = (const s16x8*)Fhi;
  const s16x8* FL = (const s16x8*)Flo;

  f32x4 acc[4][4] = {};
  for (int s = 0; s < 4; ++s) {
    s16x8 ah[4], al[4], bh[4], bl[4];
#pragma unroll
    for (int t = 0; t < 4; ++t) {
      int ia = ((mt0 + t) * 4 + s) * 64 + l;
      int ib = ((nt0 + t) * 4 + s) * 64 + l;
      ah[t] = FH[ia]; al[t] = FL[ia];
      bh[t] = FH[ib]; bl[t] = FL[ib];
    }
#pragma unroll
    for (int ti = 0; ti < 4; ++ti)
#pragma unroll
      for (int tj = 0; tj < 4; ++tj) {
        acc[ti][tj] = __builtin_amdgcn_mfma_f32_16x16x32_bf16(ah[ti], bh[tj], acc[ti][tj], 0, 0, 0);
        acc[ti][tj] = __builtin_amdgcn_mfma_f32_16x16x32_bf16(ah[ti], bl[tj], acc[ti][tj], 0, 0, 0);
        acc[ti][tj] = __builtin_amdgcn_mfma_f32_16x16x32_bf16(al[ti], bh[tj], acc[ti][tj], 0, 0, 0);
      }
  }

  int labn[4];
#pragma unroll
  for (int tj = 0; tj < 4; ++tj) labn[tj] = labels[nt0 * 16 + tj * 16 + lm16];

#pragma unroll
  for (int ti = 0; ti < 4; ++ti) {
#pragma unroll
    for (int r = 0; r < 4; ++r) {
      int m = (mt0 + ti) * 16 + lg * 4 + r;
      int lm = labels[m];
      unsigned long long pk = 0xFF800000FFFFFFFFULL;
      unsigned int nk = 0x007FFFFFu;
#pragma unroll
      for (int tj = 0; tj < 4; ++tj) {
        float sv = acc[ti][tj][r];
        int n = (nt0 + tj) * 16 + lm16;
        if (n == m) sv = 1.0f;  // diagonal: excluded by value gate below
        if (lm == labn[tj]) {
          if (sv < 1.0f - EPS_SELF) {
            unsigned long long cand = ((unsigned long long)fkey(sv) << 32) | (unsigned int)n;
            pk = pk < cand ? pk : cand;
          }
        } else {
          unsigned int ck = fkey(sv);
          nk = nk > ck ? nk : ck;
        }
      }
#pragma unroll
      for (int d = 1; d < 16; d <<= 1) {
        unsigned long long po = __shfl_xor(pk, d, 64);
        pk = pk < po ? pk : po;
        unsigned int no = __shfl_xor(nk, d, 64);
        nk = nk > no ? nk : no;
      }
      if (lm16 == 0) {
        atomicMin(&minkey[m], pk);
        atomicMax(&maxkey[m], nk);
      }
    }
  }
}

// ---------------------------------------------------------------------------
// K3g: decode keys -> row params; gather j-rows into F-layout FJ.
// One block per 16-row tile.
__global__ __launch_bounds__(256) void k3g(
    const short* __restrict__ Fhi, const short* __restrict__ Flo,
    const unsigned long long* __restrict__ minkey, const unsigned int* __restrict__ maxkey,
    float* __restrict__ minposf, float* __restrict__ maxnegf,
    float* __restrict__ dppA, float* __restrict__ inppA,
    int* __restrict__ validA, short* __restrict__ FJhi, short* __restrict__ FJlo) {
  __shared__ int s_j[16];
  int tid = threadIdx.x;
  int blk = blockIdx.x;
  if (tid < 16) {
    int i = blk * 16 + tid;
    unsigned long long mk = minkey[i];
    float minpos = keyf((unsigned int)(mk >> 32));
    float maxneg = keyf(maxkey[i]);
    bool valid = (maxneg + MARGIN > minpos);
    int j = valid ? (int)(mk & 0xFFFFFFFFu) : i;
    minposf[i] = minpos;
    maxnegf[i] = maxneg;
    dppA[i] = minpos - 1.0f;  // e_i.d_p = sim_ij - 1 (unit rows)
    inppA[i] = 1.0f / fmaxf(sqrtf(fmaxf(2.0f - 2.0f * minpos, 1e-12f)), 1e-8f);
    validA[i] = valid ? 1 : 0;
    s_j[tid] = j;
  }
  __syncthreads();
  int rrel = tid >> 4, c = tid & 15;
  int j = s_j[rrel];
  int src = ((j >> 4) * 4 + (c >> 2)) * 64 + (c & 3) * 16 + (j & 15);
  int dst = (blk * 4 + (c >> 2)) * 64 + (c & 3) * 16 + rrel;
  ((s16x8*)FJhi)[dst] = ((const s16x8*)Fhi)[src];
  ((s16x8*)FJlo)[dst] = ((const s16x8*)Flo)[src];
}

// ---------------------------------------------------------------------------
// K2b (pass 2): dual GEMM recompute (S = E_m.E^T, SJ = E_j(m).E^T) + loss
// epilogue in registers. Block 64x128 (4 waves, 32x64 each). No sim traffic.
__global__ __launch_bounds__(256) void k2b_pass2(
    const short* __restrict__ Fhi, const short* __restrict__ Flo,
    const short* __restrict__ FJhi, const short* __restrict__ FJlo,
    const int* __restrict__ labels,
    const float* __restrict__ minposf, const float* __restrict__ maxnegf,
    const float* __restrict__ dppA, const float* __restrict__ inppA,
    float* __restrict__ possum, float* __restrict__ negsum) {
  int tid = threadIdx.x;
  int w = tid >> 6, l = tid & 63;
  int lm16 = l & 15, lg = l >> 4;
  int mt0 = blockIdx.y * 4 + (w >> 1) * 2;  // 2 m-tiles per wave (32 rows)
  int nt0 = blockIdx.x * 8 + (w & 1) * 4;   // 4 n-tiles per wave (64 cols)
  const s16x8* FH = (const s16x8*)Fhi;
  const s16x8* FL = (const s16x8*)Flo;
  const s16x8* GH = (const s16x8*)FJhi;
  const s16x8* GL = (const s16x8*)FJlo;

  f32x4 accs[2][4] = {};
  f32x4 accj[2][4] = {};
  for (int s = 0; s < 4; ++s) {
    s16x8 ah[2], al[2], jh[2], jl[2], bh[4], bl[4];
#pragma unroll
    for (int t = 0; t < 2; ++t) {
      int ia = ((mt0 + t) * 4 + s) * 64 + l;
      ah[t] = FH[ia]; al[t] = FL[ia];
      jh[t] = GH[ia]; jl[t] = GL[ia];
    }
#pragma unroll
    for (int t = 0; t < 4; ++t) {
      int ib = ((nt0 + t) * 4 + s) * 64 + l;
      bh[t] = FH[ib]; bl[t] = FL[ib];
    }
#pragma unroll
    for (int ti = 0; ti < 2; ++ti)
#pragma unroll
      for (int tj = 0; tj < 4; ++tj) {
        accs[ti][tj] = __builtin_amdgcn_mfma_f32_16x16x32_bf16(ah[ti], bh[tj], accs[ti][tj], 0, 0, 0);
        accs[ti][tj] = __builtin_amdgcn_mfma_f32_16x16x32_bf16(ah[ti], bl[tj], accs[ti][tj], 0, 0, 0);
        accs[ti][tj] = __builtin_amdgcn_mfma_f32_16x16x32_bf16(al[ti], bh[tj], accs[ti][tj], 0, 0, 0);
        accj[ti][tj] = __builtin_amdgcn_mfma_f32_16x16x32_bf16(jh[ti], bh[tj], accj[ti][tj], 0, 0, 0);
        accj[ti][tj] = __builtin_amdgcn_mfma_f32_16x16x32_bf16(jh[ti], bl[tj], accj[ti][tj], 0, 0, 0);
        accj[ti][tj] = __builtin_amdgcn_mfma_f32_16x16x32_bf16(jl[ti], bh[tj], accj[ti][tj], 0, 0, 0);
      }
  }

  int labn[4];
#pragma unroll
  for (int tj = 0; tj < 4; ++tj) labn[tj] = labels[nt0 * 16 + tj * 16 + lm16];

#pragma unroll
  for (int ti = 0; ti < 2; ++ti) {
    // per-row params for rows m = (mt0+ti)*16 + lg*4 + r, r=0..3 (one float4)
    int v4 = (mt0 + ti) * 4 + lg;
    float4 mp4 = ((const float4*)minposf)[v4];
    float4 mx4 = ((const float4*)maxnegf)[v4];
    float4 dp4 = ((const float4*)dppA)[v4];
    float4 ip4 = ((const float4*)inppA)[v4];
    int4 lm4 = ((const int4*)labels)[v4];
#pragma unroll
    for (int r = 0; r < 4; ++r) {
      int m = (mt0 + ti) * 16 + lg * 4 + r;
      int lm = (&lm4.x)[r];
      float mp = (&mp4.x)[r], mx = (&mx4.x)[r];
      float dpp = (&dp4.x)[r], inpp = (&ip4.x)[r];
      float ps = 0.0f, ns = 0.0f;
#pragma unroll
      for (int tj = 0; tj < 4; ++tj) {
        float sv = accs[ti][tj][r];
        int n = (nt0 + tj) * 16 + lm16;
        if (lm == labn[tj]) {
          if (n != m && sv < 1.0f - EPS_SELF && sv - MARGIN < mx)
            ps += __expf(-SCALE_POS * (sv - THRESH));
        } else if (sv + MARGIN > mp) {
          float sj = accj[ti][tj][r];
          float nn = sqrtf(fmaxf(2.0f - 2.0f * sv, 1e-12f));
          float rg = GAMMA * (sj - sv - dpp) * inpp * __builtin_amdgcn_rcpf(nn);
          ns += __expf(SCALE_NEG * (sv - THRESH - rg));
        }
      }
#pragma unroll
      for (int d = 1; d < 16; d <<= 1) {
        ps += __shfl_xor(ps, d, 64);
        ns += __shfl_xor(ns, d, 64);
      }
      if (lm16 == 0) {
        atomicAdd(&possum[m], ps);
        atomicAdd(&negsum[m], ns);
      }
    }
  }
}

// ---------------------------------------------------------------------------
// K5: final row losses + mean. Single block, 1024 threads.
__global__ __launch_bounds__(1024) void k5_final(
    const float* __restrict__ possum, const float* __restrict__ negsum,
    const int* __restrict__ validA, float* __restrict__ out) {
  int tid = threadIdx.x;
  float local = 0.0f;
  for (int r = tid; r < NB; r += 1024) {
    if (validA[r])
      local += log1pf(possum[r]) * (1.0f / SCALE_POS) + log1pf(negsum[r]) * (1.0f / SCALE_NEG);
  }
#pragma unroll
  for (int d = 1; d < 64; d <<= 1) local += __shfl_xor(local, d, 64);
  __shared__ float partial[16];
  if ((tid & 63) == 0) partial[tid >> 6] = local;
  __syncthreads();
  if (tid == 0) {
    float t = 0.0f;
#pragma unroll
    for (int q = 0; q < 16; ++q) t += partial[q];
    out[0] = t / (float)NB;
  }
}

// ---------------------------------------------------------------------------
extern "C" void kernel_launch(void* const* d_in, const int* in_sizes, int n_in,
                              void* d_out, int out_size, void* d_ws, size_t ws_size,
                              hipStream_t stream) {
  const float* emb = (const float*)d_in[0];
  const int* labels = (const int*)d_in[1];
  float* out = (float*)d_out;
  char* ws = (char*)d_ws;

  unsigned long long* minkey = (unsigned long long*)(ws);          // 32 KB
  unsigned int* maxkey = (unsigned int*)(ws + 32768);              // 16 KB
  float* minposf = (float*)(ws + 49152);
  float* maxnegf = (float*)(ws + 65536);
  float* dppA = (float*)(ws + 81920);
  float* inppA = (float*)(ws + 98304);
  int* validA = (int*)(ws + 114688);
  float* possum = (float*)(ws + 131072);
  float* negsum = (float*)(ws + 147456);
  short* Fhi = (short*)(ws + 163840);                              // 1 MB
  short* Flo = (short*)(ws + 163840 + 1048576);                    // 1 MB
  short* FJhi = (short*)(ws + 163840 + 2097152);                   // 1 MB
  short* FJlo = (short*)(ws + 163840 + 3145728);                   // 1 MB

  hipLaunchKernelGGL(k1_convert, dim3(NB * ND / 8 / 256), dim3(256), 0, stream,
                     emb, Fhi, Flo, minkey, maxkey, possum, negsum);
  hipLaunchKernelGGL(k2a_pass1, dim3(NB / 128, NB / 128), dim3(256), 0, stream,
                     Fhi, Flo, labels, minkey, maxkey);
  hipLaunchKernelGGL(k3g, dim3(NB / 16), dim3(256), 0, stream,
                     Fhi, Flo, minkey, maxkey, minposf, maxnegf, dppA, inppA,
                     validA, FJhi, FJlo);
  hipLaunchKernelGGL(k2b_pass2, dim3(NB / 128, NB / 64), dim3(256), 0, stream,
                     Fhi, Flo, FJhi, FJlo, labels, minposf, maxnegf, dppA, inppA,
                     possum, negsum);
  hipLaunchKernelGGL(k5_final, dim3(1), dim3(1024), 0, stream,
                     possum, negsum, validA, out);
}